// Round 8
// baseline (573.179 us; speedup 1.0000x reference)
//
#include <hip/hip_runtime.h>
#include <cstdint>
#include <cstddef>

static constexpr int kT  = 2048;
static constexpr int kD  = 512;
static constexpr int kB  = 2;
static constexpr int kN  = kB * kT;   // 4096 rows
static constexpr int NB  = 512;      // persistent grid size (co-resident)

using short8 = __attribute__((ext_vector_type(8))) short;
using f32x4  = __attribute__((ext_vector_type(4))) float;
typedef unsigned short ushort;

__device__ inline ushort f2bf(float f) {
  uint32_t u = __builtin_bit_cast(uint32_t, f);
  uint32_t r = (u + 0x7FFFu + ((u >> 16) & 1u)) >> 16;
  return (ushort)r;
}

#define GLOAD_LDS16(g, l)                                         \
  __builtin_amdgcn_global_load_lds(                               \
      (const __attribute__((address_space(1))) void*)(g),         \
      (__attribute__((address_space(3))) void*)(l), 16, 0, 0)

// ---------------------------------------------------------------- shared mem union
struct __align__(16) SmemGemm {
  ushort As[3][64 * 64];
  ushort Bs[3][64 * 64];
};                                        // 48 KB
struct __align__(16) SmemAttn {
  ushort Ks[2][64 * 64];                  // 16 KB
  ushort Vt[2][64][72];                   // 18 KB
  ushort Pl[4][16][72];                   // 9 KB
};
union SmemAll { SmemGemm g; SmemAttn a; };

// ---------------------------------------------------------------- args
struct Args {
  const float *x, *cw, *cb, *ipw, *ipb, *opw, *opb;
  const float *g1, *b1n, *w1, *bb1, *w2, *bb2, *g2, *b2n;
  float *out;
  ushort *xb, *acat, *wcat, *ipwb, *opwb, *w1b, *w2b;
  ushort *convo, *qkb, *vbb, *ctx, *hb, *f1;
  float *hbuf, *attno, *f2;
  int *bar;
};

// ---------------------------------------------------------------- grid barrier
// Monotone counter: barrier k passes when cnt >= k*NB. cnt zeroed by host
// memset each call. All NB blocks co-resident by construction.
__device__ __forceinline__ void gridbar(int* cnt, int phase) {
  __syncthreads();
  if (threadIdx.x == 0) {
    __builtin_amdgcn_fence(__ATOMIC_RELEASE, "agent");
    __hip_atomic_fetch_add(cnt, 1, __ATOMIC_RELAXED, __HIP_MEMORY_SCOPE_AGENT);
    const int want = phase * NB;
    while (__hip_atomic_load(cnt, __ATOMIC_RELAXED, __HIP_MEMORY_SCOPE_AGENT) < want)
      __builtin_amdgcn_s_sleep(8);
    __builtin_amdgcn_fence(__ATOMIC_ACQUIRE, "agent");
  }
  __syncthreads();
}

// ---------------------------------------------------------------- prep phase
__device__ void prep_phase(const Args& a, int bid) {
  constexpr int C0 = 524288;            // xb cast (float4 units)
  constexpr int C1 = C0 + 196608;       // ipw
  constexpr int C2 = C1 + 65536;        // opw
  constexpr int C3 = C2 + 131072;       // w1
  constexpr int C4 = C3 + 131072;       // w2
  constexpr int C5 = C4 + 262144;       // convw transform (o,i units)
  constexpr int C6 = C5 + 786432;       // acat (m,tap,i8 units)

  auto cast4 = [](const float* in, ushort* out, int u) {
    float4 v = *reinterpret_cast<const float4*>(&in[(size_t)u * 4]);
    ushort o[4] = {f2bf(v.x), f2bf(v.y), f2bf(v.z), f2bf(v.w)};
    *reinterpret_cast<uint2*>(&out[(size_t)u * 4]) =
        *reinterpret_cast<uint2*>(o);
  };

  for (int u = bid * 256 + threadIdx.x; u < C6; u += NB * 256) {
    if (u < C0) {
      cast4(a.x, a.xb, u);
    } else if (u < C1) {
      cast4(a.ipw, a.ipwb, u - C0);
    } else if (u < C2) {
      cast4(a.opw, a.opwb, u - C1);
    } else if (u < C3) {
      cast4(a.w1, a.w1b, u - C2);
    } else if (u < C4) {
      cast4(a.w2, a.w2b, u - C3);
    } else if (u < C5) {
      int t = u - C4;
      int o = t >> 9, i = t & 511;
      const float* src = &a.cw[(size_t)(o * kD + i) * 3];
      ushort* dst = &a.wcat[(size_t)o * (3 * kD) + i];
#pragma unroll
      for (int tap = 0; tap < 3; ++tap) dst[tap * kD] = f2bf(src[tap]);
    } else {
      int t = u - C5;
      int m = t / 192, r = t - m * 192;
      int tap = r >> 6, i8 = r & 63;
      int tib = (m & (kT - 1)) + tap - 1;
      ushort ob[8] = {0, 0, 0, 0, 0, 0, 0, 0};
      if (tib >= 0 && tib < kT) {
        const float* src = &a.x[(size_t)(m + tap - 1) * kD + i8 * 8];
        float4 v0 = *reinterpret_cast<const float4*>(src);
        float4 v1 = *reinterpret_cast<const float4*>(src + 4);
        ob[0] = f2bf(v0.x); ob[1] = f2bf(v0.y); ob[2] = f2bf(v0.z);
        ob[3] = f2bf(v0.w); ob[4] = f2bf(v1.x); ob[5] = f2bf(v1.y);
        ob[6] = f2bf(v1.z); ob[7] = f2bf(v1.w);
      }
      *reinterpret_cast<uint4*>(
          &a.acat[(size_t)m * (3 * kD) + tap * kD + i8 * 8]) =
          *reinterpret_cast<uint4*>(ob);
    }
  }
}

// ---------------------------------------------------------------- GEMM tile
// One 64x64 output tile: C = A[M,K] @ W[Nn,K]^T + bias. BK=64, 4 waves (2x2),
// 3-buffer LDS ring, 2-deep prefetch, counted vmcnt, XOR swizzle.
template <typename OutT, int RELU>
__device__ void gemm_tile(SmemGemm& S,
    const ushort* __restrict__ A, const ushort* __restrict__ W,
    const float* __restrict__ bias, OutT* __restrict__ C,
    int Nn, int K, int m0, int n0)
{
  const int tid = threadIdx.x;
  const int lane = tid & 63, w = tid >> 6;
  const int wr = w >> 1, wc = w & 1;
  const int fr = lane & 15, g = lane >> 4;

  __syncthreads();   // LDS safe to overwrite (prev tile/phase done reading)

  f32x4 acc[2][2];
#pragma unroll
  for (int i = 0; i < 2; ++i)
#pragma unroll
    for (int j = 0; j < 2; ++j) acc[i][j] = {0.f, 0.f, 0.f, 0.f};

  const int u0 = tid, u1 = tid + 256;
  const int r0s = u0 >> 3, c0s = (u0 & 7) ^ (r0s & 7);
  const int r1s = u1 >> 3, c1s = (u1 & 7) ^ (r1s & 7);
  const ushort* gA0 = A + (size_t)(m0 + r0s) * K + c0s * 8;
  const ushort* gA1 = A + (size_t)(m0 + r1s) * K + c1s * 8;
  const ushort* gB0 = W + (size_t)(n0 + r0s) * K + c0s * 8;
  const ushort* gB1 = W + (size_t)(n0 + r1s) * K + c1s * 8;
  const int ld0 = w * 512;          // ushort offset, wave-uniform
  const int ld1 = 2048 + w * 512;

  auto stage = [&](int buf, int k0) {
    GLOAD_LDS16(gA0 + k0, &S.As[buf][ld0]);
    GLOAD_LDS16(gA1 + k0, &S.As[buf][ld1]);
    GLOAD_LDS16(gB0 + k0, &S.Bs[buf][ld0]);
    GLOAD_LDS16(gB1 + k0, &S.Bs[buf][ld1]);
  };

  const int nt = K >> 6;
  stage(0, 0);
  stage(1, 64);
  int cur = 0, b2 = 2;
  for (int t = 0; t < nt; ++t) {
    if (t + 2 < nt) {
      stage(b2, (t + 2) << 6);
      asm volatile("s_waitcnt vmcnt(8)" ::: "memory");
    } else if (t + 1 < nt) {
      asm volatile("s_waitcnt vmcnt(4)" ::: "memory");
    } else {
      asm volatile("s_waitcnt vmcnt(0)" ::: "memory");
    }
    __builtin_amdgcn_s_barrier();
    __builtin_amdgcn_sched_barrier(0);

    short8 av[2][2], bv[2][2];
#pragma unroll
    for (int m = 0; m < 2; ++m)
#pragma unroll
      for (int kc = 0; kc < 2; ++kc) {
        int r = wr * 32 + m * 16 + fr;
        av[m][kc] = *reinterpret_cast<const short8*>(
            &S.As[cur][r * 64 + (((kc * 4 + g) ^ (r & 7)) * 8)]);
      }
#pragma unroll
    for (int n = 0; n < 2; ++n)
#pragma unroll
      for (int kc = 0; kc < 2; ++kc) {
        int r = wc * 32 + n * 16 + fr;
        bv[n][kc] = *reinterpret_cast<const short8*>(
            &S.Bs[cur][r * 64 + (((kc * 4 + g) ^ (r & 7)) * 8)]);
      }
#pragma unroll
    for (int m = 0; m < 2; ++m)
#pragma unroll
      for (int n = 0; n < 2; ++n)
#pragma unroll
        for (int kc = 0; kc < 2; ++kc)
          acc[m][n] = __builtin_amdgcn_mfma_f32_16x16x32_bf16(
              av[m][kc], bv[n][kc], acc[m][n], 0, 0, 0);

    __builtin_amdgcn_sched_barrier(0);
    __builtin_amdgcn_s_barrier();
    cur = cur == 2 ? 0 : cur + 1;
    b2 = b2 == 2 ? 0 : b2 + 1;
  }

  float bb[2];
#pragma unroll
  for (int n = 0; n < 2; ++n) bb[n] = bias[n0 + wc * 32 + n * 16 + fr];
#pragma unroll
  for (int m = 0; m < 2; ++m) {
#pragma unroll
    for (int j = 0; j < 4; ++j) {
      int row = m0 + wr * 32 + m * 16 + g * 4 + j;
#pragma unroll
      for (int n = 0; n < 2; ++n) {
        int col = n0 + wc * 32 + n * 16 + fr;
        float v = acc[m][n][j] + bb[n];
        if (RELU) v = fmaxf(v, 0.f);
        if constexpr (sizeof(OutT) == 2)
          C[(size_t)row * Nn + col] = (OutT)f2bf(v);
        else
          C[(size_t)row * Nn + col] = (OutT)v;
      }
    }
  }
}

// ---------------------------------------------------------------- attention tile
// One (b,h,64 q-rows) unit. Double-buffered K (global_load_lds) + V (reg->LDS).
__device__ void attn_tile(SmemAttn& S, const Args& a, int bid) {
  const int tid = threadIdx.x;
  const int lane = tid & 63, w = tid >> 6;
  const int l15 = lane & 15, g = lane >> 4;
  const int qt = bid & 31, bh = bid >> 5;
  const int b = bh >> 3, h = bh & 7;
  const int r0 = qt * 64;
  const int rowbase = b * kT;
  const int qrow0 = r0 + w * 16;
  const int t_lo = max(r0 - 256, 0);
  const int t_last = min(r0 + 256, kT - 64);
  const int ntiles = ((t_last - t_lo) >> 6) + 1;
  const ushort* QK = a.qkb;
  const ushort* V = a.vbb;

  __syncthreads();   // LDS handoff from previous phase

  short8 qf[2];
  {
    const size_t qb = (size_t)(rowbase + qrow0 + l15) * 1024 + h * 64 + g * 8;
    qf[0] = *reinterpret_cast<const short8*>(&QK[qb]);
    qf[1] = *reinterpret_cast<const short8*>(&QK[qb + 32]);
  }

  uint4 vreg[2];
  auto issueK = [&](int buf, int j0) {
#pragma unroll
    for (int c = 0; c < 2; ++c) {
      int u = c * 256 + tid;
      int row = u >> 3;
      int col8 = (u & 7) ^ (row & 7);
      const ushort* src =
          &QK[(size_t)(rowbase + j0 + row) * 1024 + 512 + h * 64 + col8 * 8];
      GLOAD_LDS16(src, &S.Ks[buf][(c * 256 + w * 64) * 8]);
    }
  };
  auto issueV = [&](int j0) {
#pragma unroll
    for (int i = 0; i < 2; ++i)
      vreg[i] = *reinterpret_cast<const uint4*>(
          &V[(size_t)(rowbase + j0 + lane) * 512 + h * 64 + (w + 4 * i) * 8]);
  };
  auto writeV = [&](int buf) {
#pragma unroll
    for (int i = 0; i < 2; ++i) {
      int dg = w + 4 * i;
      ushort tmp[8];
      *reinterpret_cast<uint4*>(tmp) = vreg[i];
#pragma unroll
      for (int e = 0; e < 8; ++e) S.Vt[buf][dg * 8 + e][lane] = tmp[e];
    }
  };

  f32x4 acc[4];
#pragma unroll
  for (int d = 0; d < 4; ++d) acc[d] = {0.f, 0.f, 0.f, 0.f};
  float mrun[4] = {-1e30f, -1e30f, -1e30f, -1e30f};
  float lrun[4] = {0.f, 0.f, 0.f, 0.f};

  issueK(0, t_lo);
  issueV(t_lo);
  asm volatile("s_waitcnt vmcnt(0)" ::: "memory");
  writeV(0);
  __syncthreads();

  for (int tt = 0; tt < ntiles; ++tt) {
    const int buf = tt & 1;
    const int j0 = t_lo + tt * 64;
    if (tt + 1 < ntiles) {
      issueK(buf ^ 1, j0 + 64);
      issueV(j0 + 64);
    }

    f32x4 s[4];
#pragma unroll
    for (int n = 0; n < 4; ++n) {
      f32x4 z = {0.f, 0.f, 0.f, 0.f};
#pragma unroll
      for (int kc = 0; kc < 2; ++kc) {
        int row = n * 16 + l15;
        int unit = row * 8 + ((kc * 4 + g) ^ (row & 7));
        short8 kb = *reinterpret_cast<const short8*>(&S.Ks[buf][unit * 8]);
        z = __builtin_amdgcn_mfma_f32_16x16x32_bf16(qf[kc], kb, z, 0, 0, 0);
      }
      s[n] = z;
    }
#pragma unroll
    for (int n = 0; n < 4; ++n)
#pragma unroll
      for (int j = 0; j < 4; ++j) {
        int col = j0 + n * 16 + l15;
        int qr = qrow0 + g * 4 + j;
        int dlt = col - qr;
        float v = s[n][j] * 0.125f;
        s[n][j] = (dlt > 256 || dlt < -256) ? -1e30f : v;
      }
    float pn[4][4];
    float sold[4];
#pragma unroll
    for (int j = 0; j < 4; ++j) {
      float mx = fmaxf(fmaxf(s[0][j], s[1][j]), fmaxf(s[2][j], s[3][j]));
      mx = fmaxf(mx, __shfl_xor(mx, 1));
      mx = fmaxf(mx, __shfl_xor(mx, 2));
      mx = fmaxf(mx, __shfl_xor(mx, 4));
      mx = fmaxf(mx, __shfl_xor(mx, 8));
      float mnew = fmaxf(mrun[j], mx);
      float sc = __expf(mrun[j] - mnew);
      mrun[j] = mnew;
      sold[j] = sc;
      float rs = 0.f;
#pragma unroll
      for (int n = 0; n < 4; ++n) {
        float p = __expf(s[n][j] - mnew);
        pn[n][j] = p;
        rs += p;
      }
      rs += __shfl_xor(rs, 1);
      rs += __shfl_xor(rs, 2);
      rs += __shfl_xor(rs, 4);
      rs += __shfl_xor(rs, 8);
      lrun[j] = lrun[j] * sc + rs;
    }
#pragma unroll
    for (int d = 0; d < 4; ++d)
#pragma unroll
      for (int j = 0; j < 4; ++j) acc[d][j] *= sold[j];
#pragma unroll
    for (int n = 0; n < 4; ++n)
#pragma unroll
      for (int j = 0; j < 4; ++j)
        S.Pl[w][g * 4 + j][n * 16 + l15] = f2bf(pn[n][j]);
    asm volatile("s_waitcnt lgkmcnt(0)" ::: "memory");
    __builtin_amdgcn_sched_barrier(0);

    short8 pa[2];
    pa[0] = *reinterpret_cast<const short8*>(&S.Pl[w][l15][g * 8]);
    pa[1] = *reinterpret_cast<const short8*>(&S.Pl[w][l15][32 + g * 8]);
#pragma unroll
    for (int d = 0; d < 4; ++d) {
#pragma unroll
      for (int kc = 0; kc < 2; ++kc) {
        short8 vb = *reinterpret_cast<const short8*>(
            &S.Vt[buf][d * 16 + l15][kc * 32 + g * 8]);
        acc[d] = __builtin_amdgcn_mfma_f32_16x16x32_bf16(pa[kc], vb, acc[d], 0, 0, 0);
      }
    }

    if (tt + 1 < ntiles) {
      asm volatile("s_waitcnt vmcnt(0)" ::: "memory");
      writeV(buf ^ 1);
    }
    __syncthreads();
  }

  float inv[4];
#pragma unroll
  for (int j = 0; j < 4; ++j) inv[j] = 1.f / lrun[j];
#pragma unroll
  for (int d = 0; d < 4; ++d)
#pragma unroll
    for (int j = 0; j < 4; ++j) {
      float v = acc[d][j] * inv[j];
      a.ctx[(size_t)(rowbase + qrow0 + g * 4 + j) * 512 + h * 64 + d * 16 + l15] =
          f2bf(v);
    }
}

// ---------------------------------------------------------------- LN rows
__device__ void ln_rows(const float* __restrict__ A, const float* __restrict__ Bq,
                        const float* __restrict__ G, const float* __restrict__ Bt,
                        float* __restrict__ Out, ushort* __restrict__ OutB,
                        int bid)
{
  const int lane = threadIdx.x & 63;
  const int wv = threadIdx.x >> 6;
#pragma unroll
  for (int rr = 0; rr < 2; ++rr) {
    const int row = bid * 8 + wv * 2 + rr;
    const size_t base = (size_t)row * kD + lane * 8;

    float4 a0 = *reinterpret_cast<const float4*>(&A[base]);
    float4 a1 = *reinterpret_cast<const float4*>(&A[base + 4]);
    float4 b0 = *reinterpret_cast<const float4*>(&Bq[base]);
    float4 b1 = *reinterpret_cast<const float4*>(&Bq[base + 4]);
    float x[8] = {a0.x + b0.x, a0.y + b0.y, a0.z + b0.z, a0.w + b0.w,
                  a1.x + b1.x, a1.y + b1.y, a1.z + b1.z, a1.w + b1.w};
    float s = 0.f, ss = 0.f;
#pragma unroll
    for (int i = 0; i < 8; ++i) { s += x[i]; ss += x[i] * x[i]; }
#pragma unroll
    for (int o = 1; o < 64; o <<= 1) {
      s += __shfl_xor(s, o, 64);
      ss += __shfl_xor(ss, o, 64);
    }
    const float mean = s * (1.f / kD);
    const float var = ss * (1.f / kD) - mean * mean;
    const float rs = rsqrtf(var + 1e-5f);

    const int c = lane * 8;
    float4 g0 = *reinterpret_cast<const float4*>(&G[c]);
    float4 g1 = *reinterpret_cast<const float4*>(&G[c + 4]);
    float4 t0 = *reinterpret_cast<const float4*>(&Bt[c]);
    float4 t1 = *reinterpret_cast<const float4*>(&Bt[c + 4]);
    float y[8];
    y[0] = (x[0] - mean) * rs * g0.x + t0.x;
    y[1] = (x[1] - mean) * rs * g0.y + t0.y;
    y[2] = (x[2] - mean) * rs * g0.z + t0.z;
    y[3] = (x[3] - mean) * rs * g0.w + t0.w;
    y[4] = (x[4] - mean) * rs * g1.x + t1.x;
    y[5] = (x[5] - mean) * rs * g1.y + t1.y;
    y[6] = (x[6] - mean) * rs * g1.z + t1.z;
    y[7] = (x[7] - mean) * rs * g1.w + t1.w;
    *reinterpret_cast<float4*>(&Out[base]) = {y[0], y[1], y[2], y[3]};
    *reinterpret_cast<float4*>(&Out[base + 4]) = {y[4], y[5], y[6], y[7]};
    if (OutB) {
      ushort ob[8];
#pragma unroll
      for (int i = 0; i < 8; ++i) ob[i] = f2bf(y[i]);
      *reinterpret_cast<uint4*>(&OutB[base]) = *reinterpret_cast<uint4*>(ob);
    }
  }
}

// ---------------------------------------------------------------- megakernel
__global__ __launch_bounds__(256, 2) void mega_kernel(Args a) {
  __shared__ SmemAll sm;
  const int bid = blockIdx.x;

  // P0: prep (casts, conv-weight transform, im2col)
  prep_phase(a, bid);
  gridbar(a.bar, 1);

  // P1: conv GEMM (512 tiles) + qk proj (1024 tiles), 3 tiles/block
  gemm_tile<ushort, 0>(sm.g, a.acat, a.wcat, a.cb, a.convo,
                       kD, 3 * kD, (bid >> 3) * 64, (bid & 7) * 64);
  {
    int q0 = bid, q1 = bid + 512;   // qk tile ids in 64x16 grid
    gemm_tile<ushort, 0>(sm.g, a.xb, a.ipwb, a.ipb, a.qkb,
                         1024, kD, (q0 >> 4) * 64, (q0 & 15) * 64);
    gemm_tile<ushort, 0>(sm.g, a.xb, a.ipwb, a.ipb, a.qkb,
                         1024, kD, (q1 >> 4) * 64, (q1 & 15) * 64);
  }
  gridbar(a.bar, 2);

  // P2: v projection (512 tiles)
  gemm_tile<ushort, 0>(sm.g, a.convo, a.ipwb + (size_t)1024 * kD,
                       a.ipb + 1024, a.vbb, kD, kD,
                       (bid >> 3) * 64, (bid & 7) * 64);
  gridbar(a.bar, 3);

  // P3: banded attention (512 units)
  attn_tile(sm.a, a, bid);
  gridbar(a.bar, 4);

  // P4: out projection (512 tiles)
  gemm_tile<float, 0>(sm.g, a.ctx, a.opwb, a.opb, a.attno,
                      kD, kD, (bid >> 3) * 64, (bid & 7) * 64);
  gridbar(a.bar, 5);

  // P5: h = LN(x + attn_out)
  ln_rows(a.x, a.attno, a.g1, a.b1n, a.hbuf, a.hb, bid);
  gridbar(a.bar, 6);

  // P6: ffn1 = relu(h @ w1^T + b1), 1024 tiles, 2/block
  gemm_tile<ushort, 1>(sm.g, a.hb, a.w1b, a.bb1, a.f1,
                       1024, kD, (bid >> 4) * 64, (bid & 15) * 64);
  gemm_tile<ushort, 1>(sm.g, a.hb, a.w1b, a.bb1, a.f1,
                       1024, kD, ((bid + 512) >> 4) * 64, ((bid + 512) & 15) * 64);
  gridbar(a.bar, 7);

  // P7: ffn2 (512 tiles)
  gemm_tile<float, 0>(sm.g, a.f1, a.w2b, a.bb2, a.f2,
                      kD, 2 * kD, (bid >> 3) * 64, (bid & 7) * 64);
  gridbar(a.bar, 8);

  // P8: out = LN(h + ffn2)
  ln_rows(a.hbuf, a.f2, a.g2, a.b2n, a.out, nullptr, bid);
}

// ---------------------------------------------------------------- launch
extern "C" void kernel_launch(void* const* d_in, const int* in_sizes, int n_in,
                              void* d_out, int out_size, void* d_ws, size_t ws_size,
                              hipStream_t stream)
{
  Args a;
  a.x   = (const float*)d_in[0];
  a.cw  = (const float*)d_in[2];
  a.cb  = (const float*)d_in[3];
  a.ipw = (const float*)d_in[4];
  a.ipb = (const float*)d_in[5];
  a.opw = (const float*)d_in[6];
  a.opb = (const float*)d_in[7];
  a.g1  = (const float*)d_in[8];
  a.b1n = (const float*)d_in[9];
  a.w1  = (const float*)d_in[10];
  a.bb1 = (const float*)d_in[11];
  a.w2  = (const float*)d_in[12];
  a.bb2 = (const float*)d_in[13];
  a.g2  = (const float*)d_in[14];
  a.b2n = (const float*)d_in[15];
  a.out = (float*)d_out;

  char* p = (char*)d_ws;
  auto take = [&](size_t bytes) {
    char* q = p; p += (bytes + 255) & ~size_t(255); return q;
  };
  a.bar  = (int*)take(256);
  a.xb   = (ushort*)take((size_t)kN * kD * 2);
  char* acat_r =      take((size_t)kN * 3 * kD * 2);   // 12MB region
  a.acat = (ushort*)acat_r;
  a.wcat = (ushort*)take((size_t)kD * 3 * kD * 2);
  a.ipwb = (ushort*)take((size_t)3 * kD * kD * 2);
  a.opwb = (ushort*)take((size_t)kD * kD * 2);
  a.w1b  = (ushort*)take((size_t)2 * kD * kD * 2);
  a.w2b  = (ushort*)take((size_t)2 * kD * kD * 2);
  a.convo= (ushort*)take((size_t)kN * kD * 2);
  char* qk_r =        take((size_t)kN * 2 * kD * 2);   // 8MB bf16 q|k
  a.qkb  = (ushort*)qk_r;
  a.vbb  = (ushort*)take((size_t)kN * kD * 2);
  a.ctx  = (ushort*)take((size_t)kN * kD * 2);
  a.hbuf = (float*)take((size_t)kN * kD * 4);
  a.hb   = (ushort*)take((size_t)kN * kD * 2);
  a.attno= (float*)acat_r;        // acat dead after P1
  a.f1   = (ushort*)qk_r;         // qkb dead after attention
  a.f2   = (float*)take((size_t)kN * kD * 4);

  (void)hipMemsetAsync(a.bar, 0, 256, stream);
  mega_kernel<<<dim3(NB), dim3(256), 0, stream>>>(a);
}

// Round 9
// 205.022 us; speedup vs baseline: 2.7957x; 2.7957x over previous
//
#include <hip/hip_runtime.h>
#include <cstdint>
#include <cstddef>

static constexpr int kT  = 2048;
static constexpr int kD  = 512;
static constexpr int kB  = 2;
static constexpr int kN  = kB * kT;   // 4096 rows

using short8 = __attribute__((ext_vector_type(8))) short;
using f32x4  = __attribute__((ext_vector_type(4))) float;
typedef unsigned short ushort;

__device__ inline ushort f2bf(float f) {
  uint32_t u = __builtin_bit_cast(uint32_t, f);
  uint32_t r = (u + 0x7FFFu + ((u >> 16) & 1u)) >> 16;
  return (ushort)r;
}

#define GLOAD_LDS16(g, l)                                         \
  __builtin_amdgcn_global_load_lds(                               \
      (const __attribute__((address_space(1))) void*)(g),         \
      (__attribute__((address_space(3))) void*)(l), 16, 0, 0)

struct __align__(16) SmemGemm {
  ushort As[2][64 * 128];
  ushort Bs[2][64 * 128];
};                                        // 64 KB

// ---------------------------------------------------------------- fused prep
// casts, conv-weight transpose (wct[ti][c] = cw[c][i][tap]), im2col acat,
// and 8-way partials of Wv@cb for the fused conv+v bias.
__global__ __launch_bounds__(256) void prep_kernel(
    const float* __restrict__ x,   const float* __restrict__ ipw,
    const float* __restrict__ opw, const float* __restrict__ w1,
    const float* __restrict__ w2,  const float* __restrict__ cw,
    const float* __restrict__ cb,
    ushort* __restrict__ xb,   ushort* __restrict__ ipwb,
    ushort* __restrict__ opwb, ushort* __restrict__ w1b,
    ushort* __restrict__ w2b,  ushort* __restrict__ wct,
    ushort* __restrict__ acat, float* __restrict__ bvpart)
{
  constexpr int C0 = 524288;            // xb cast (float4 units)
  constexpr int C1 = C0 + 196608;       // ipw
  constexpr int C2 = C1 + 65536;        // opw
  constexpr int C3 = C2 + 131072;       // w1
  constexpr int C4 = C3 + 131072;       // w2
  constexpr int C5 = C4 + 786432;       // wct (ti,c) units
  constexpr int C6 = C5 + 786432;       // acat (m,tap,i8) units
  constexpr int C7 = C6 + 4096;         // bvpart (o,seg) units

  auto cast4 = [](const float* in, ushort* out, int u) {
    float4 v = *reinterpret_cast<const float4*>(&in[(size_t)u * 4]);
    ushort o[4] = {f2bf(v.x), f2bf(v.y), f2bf(v.z), f2bf(v.w)};
    *reinterpret_cast<uint2*>(&out[(size_t)u * 4]) =
        *reinterpret_cast<uint2*>(o);
  };

  for (int u = blockIdx.x * 256 + threadIdx.x; u < C7; u += gridDim.x * 256) {
    if (u < C0) {
      cast4(x, xb, u);
    } else if (u < C1) {
      cast4(ipw, ipwb, u - C0);
    } else if (u < C2) {
      cast4(opw, opwb, u - C1);
    } else if (u < C3) {
      cast4(w1, w1b, u - C2);
    } else if (u < C4) {
      cast4(w2, w2b, u - C3);
    } else if (u < C5) {
      int t = u - C4;
      int ti = t >> 9, c = t & 511;        // ti = tap*512 + i
      int tap = ti >> 9, i = ti & 511;
      wct[(size_t)ti * 512 + c] = f2bf(cw[((size_t)c * 512 + i) * 3 + tap]);
    } else if (u < C6) {
      int t = u - C5;
      int m = t / 192, r = t - m * 192;
      int tap = r >> 6, i8 = r & 63;
      int tib = (m & (kT - 1)) + tap - 1;
      ushort ob[8] = {0, 0, 0, 0, 0, 0, 0, 0};
      if (tib >= 0 && tib < kT) {
        const float* src = &x[(size_t)(m + tap - 1) * kD + i8 * 8];
        float4 v0 = *reinterpret_cast<const float4*>(src);
        float4 v1 = *reinterpret_cast<const float4*>(src + 4);
        ob[0] = f2bf(v0.x); ob[1] = f2bf(v0.y); ob[2] = f2bf(v0.z);
        ob[3] = f2bf(v0.w); ob[4] = f2bf(v1.x); ob[5] = f2bf(v1.y);
        ob[6] = f2bf(v1.z); ob[7] = f2bf(v1.w);
      }
      *reinterpret_cast<uint4*>(
          &acat[(size_t)m * (3 * kD) + tap * kD + i8 * 8]) =
          *reinterpret_cast<uint4*>(ob);
    } else {
      int t = u - C6;
      int o = t >> 3, seg = t & 7;
      float s = 0.f;
      const float* wr = &ipw[(size_t)(1024 + o) * kD + seg * 64];
      const float* cr = &cb[seg * 64];
#pragma unroll 8
      for (int c = 0; c < 64; ++c) s = fmaf(wr[c], cr[c], s);
      bvpart[t] = s;
    }
  }
}

// ---------------------------------------------------------------- GEMM tile (device)
// One 64x64 tile: C = A[.,K] @ W[Nn,K]^T + bias. BK=128, 4 waves (2x2),
// 2-buffer LDS, 1-ahead prefetch, counted vmcnt, XOR swizzle.
template <typename OutT, int RELU>
__device__ void gemm_tile(SmemGemm& S,
    const ushort* __restrict__ A, const ushort* __restrict__ W,
    const float* __restrict__ bias, OutT* __restrict__ C,
    int Nn, int K, int m0, int n0)
{
  const int tid = threadIdx.x;
  const int lane = tid & 63, w = tid >> 6;
  const int wr = w >> 1, wc = w & 1;
  const int fr = lane & 15, g = lane >> 4;

  f32x4 acc[2][2];
#pragma unroll
  for (int i = 0; i < 2; ++i)
#pragma unroll
    for (int j = 0; j < 2; ++j) acc[i][j] = {0.f, 0.f, 0.f, 0.f};

  const ushort* gA[4];
  const ushort* gB[4];
#pragma unroll
  for (int i = 0; i < 4; ++i) {
    int u = i * 256 + tid;
    int row = u >> 4, c = (u & 15) ^ (row & 7);
    gA[i] = A + (size_t)(m0 + row) * K + c * 8;
    gB[i] = W + (size_t)(n0 + row) * K + c * 8;
  }

  auto stage = [&](int buf, int k0) {
#pragma unroll
    for (int i = 0; i < 4; ++i)
      GLOAD_LDS16(gA[i] + k0, &S.As[buf][(i * 256 + w * 64) * 8]);
#pragma unroll
    for (int i = 0; i < 4; ++i)
      GLOAD_LDS16(gB[i] + k0, &S.Bs[buf][(i * 256 + w * 64) * 8]);
  };

  const int nt = K >> 7;
  stage(0, 0);
  for (int t = 0; t < nt; ++t) {
    const int buf = t & 1;
    if (t + 1 < nt) {
      stage(buf ^ 1, (t + 1) << 7);
      asm volatile("s_waitcnt vmcnt(8)" ::: "memory");
    } else {
      asm volatile("s_waitcnt vmcnt(0)" ::: "memory");
    }
    __builtin_amdgcn_s_barrier();
    __builtin_amdgcn_sched_barrier(0);

    short8 av[2][4], bv[2][4];
#pragma unroll
    for (int m = 0; m < 2; ++m)
#pragma unroll
      for (int kc = 0; kc < 4; ++kc) {
        int r = wr * 32 + m * 16 + fr;
        av[m][kc] = *reinterpret_cast<const short8*>(
            &S.As[buf][(r * 16 + ((kc * 4 + g) ^ (r & 7))) * 8]);
      }
#pragma unroll
    for (int n = 0; n < 2; ++n)
#pragma unroll
      for (int kc = 0; kc < 4; ++kc) {
        int r = wc * 32 + n * 16 + fr;
        bv[n][kc] = *reinterpret_cast<const short8*>(
            &S.Bs[buf][(r * 16 + ((kc * 4 + g) ^ (r & 7))) * 8]);
      }
#pragma unroll
    for (int m = 0; m < 2; ++m)
#pragma unroll
      for (int n = 0; n < 2; ++n)
#pragma unroll
        for (int kc = 0; kc < 4; ++kc)
          acc[m][n] = __builtin_amdgcn_mfma_f32_16x16x32_bf16(
              av[m][kc], bv[n][kc], acc[m][n], 0, 0, 0);

    __builtin_amdgcn_sched_barrier(0);
    __builtin_amdgcn_s_barrier();
  }

  float bb[2];
#pragma unroll
  for (int n = 0; n < 2; ++n)
    bb[n] = bias ? bias[n0 + wc * 32 + n * 16 + fr] : 0.f;
#pragma unroll
  for (int m = 0; m < 2; ++m) {
#pragma unroll
    for (int j = 0; j < 4; ++j) {
      int row = m0 + wr * 32 + m * 16 + g * 4 + j;
#pragma unroll
      for (int n = 0; n < 2; ++n) {
        int col = n0 + wc * 32 + n * 16 + fr;
        float v = acc[m][n][j] + bb[n];
        if (RELU) v = fmaxf(v, 0.f);
        if constexpr (sizeof(OutT) == 2)
          C[(size_t)row * Nn + col] = (OutT)f2bf(v);
        else
          C[(size_t)row * Nn + col] = (OutT)v;
      }
    }
  }
}

// ---------------------------------------------------------------- GEMM kernels
template <typename OutT, int RELU>
__global__ __launch_bounds__(256) void gemm_bf16(
    const ushort* __restrict__ A, const ushort* __restrict__ W,
    const float* __restrict__ bias, OutT* __restrict__ C, int Nn, int K)
{
  __shared__ SmemGemm S;
  gemm_tile<OutT, RELU>(S, A, W, bias, C, Nn, K,
                        blockIdx.x * 64, blockIdx.y * 64);
}

// Wv_eff = Wv @ Wc (per-tap), plus bveff reduction.
__global__ __launch_bounds__(256) void wprep_kernel(
    const ushort* __restrict__ ipwb, const ushort* __restrict__ wct,
    ushort* __restrict__ wveff, const float* __restrict__ ipb,
    const float* __restrict__ bvpart, float* __restrict__ bveff)
{
  __shared__ SmemGemm S;
  const int bid = blockIdx.x;
  const int m0 = (bid / 24) * 64, n0 = (bid % 24) * 64;
  gemm_tile<ushort, 0>(S, ipwb + (size_t)1024 * kD, wct, nullptr, wveff,
                       3 * kD, kD, m0, n0);
  if (bid < 2) {
    int o = bid * 256 + threadIdx.x;
    float s = ipb[1024 + o];
#pragma unroll
    for (int e = 0; e < 8; ++e) s += bvpart[o * 8 + e];
    bveff[o] = s;
  }
}

// q,k (from xb, K=512) and v (from acat, K=1536, fused conv) in one launch.
__global__ __launch_bounds__(256) void qkv_kernel(
    const ushort* __restrict__ xb, const ushort* __restrict__ acat,
    const ushort* __restrict__ ipwb, const float* __restrict__ ipb,
    const ushort* __restrict__ wveff, const float* __restrict__ bveff,
    ushort* __restrict__ qkb, ushort* __restrict__ vbb)
{
  __shared__ SmemGemm S;
  const int bid = blockIdx.x;
  if (bid < 1024) {
    gemm_tile<ushort, 0>(S, xb, ipwb, ipb, qkb, 1024, kD,
                         (bid >> 4) * 64, (bid & 15) * 64);
  } else {
    const int t = bid - 1024;
    gemm_tile<ushort, 0>(S, acat, wveff, bveff, vbb, kD, 3 * kD,
                         (t >> 3) * 64, (t & 7) * 64);
  }
}

// ---------------------------------------------------------------- banded MFMA attention
__global__ __launch_bounds__(256) void attn_mfma(
    const ushort* __restrict__ QK, const ushort* __restrict__ V,
    ushort* __restrict__ Ctx)
{
  constexpr int PAD = 72;
  __shared__ __align__(16) ushort Ks[2][64 * 64];
  __shared__ __align__(16) ushort Vt[2][64][PAD];
  __shared__ __align__(16) ushort Pl[4][16][PAD];
  const int tid = threadIdx.x;
  const int lane = tid & 63, w = tid >> 6;
  const int l15 = lane & 15, g = lane >> 4;
  const int bh = blockIdx.y;
  const int b = bh >> 3, h = bh & 7;
  const int r0 = blockIdx.x * 64;
  const int rowbase = b * kT;
  const int qrow0 = r0 + w * 16;
  const int t_lo = max(r0 - 256, 0);
  const int t_last = min(r0 + 256, kT - 64);
  const int ntiles = ((t_last - t_lo) >> 6) + 1;

  short8 qf[2];
  {
    const size_t qb = (size_t)(rowbase + qrow0 + l15) * 1024 + h * 64 + g * 8;
    qf[0] = *reinterpret_cast<const short8*>(&QK[qb]);
    qf[1] = *reinterpret_cast<const short8*>(&QK[qb + 32]);
  }

  uint4 vreg[2];
  auto issueK = [&](int buf, int j0) {
#pragma unroll
    for (int c = 0; c < 2; ++c) {
      int u = c * 256 + tid;
      int row = u >> 3;
      int col8 = (u & 7) ^ (row & 7);
      const ushort* src =
          &QK[(size_t)(rowbase + j0 + row) * 1024 + 512 + h * 64 + col8 * 8];
      GLOAD_LDS16(src, &Ks[buf][(c * 256 + w * 64) * 8]);
    }
  };
  auto issueV = [&](int j0) {
#pragma unroll
    for (int i = 0; i < 2; ++i)
      vreg[i] = *reinterpret_cast<const uint4*>(
          &V[(size_t)(rowbase + j0 + lane) * 512 + h * 64 + (w + 4 * i) * 8]);
  };
  auto writeV = [&](int buf) {
#pragma unroll
    for (int i = 0; i < 2; ++i) {
      int dg = w + 4 * i;
      ushort tmp[8];
      *reinterpret_cast<uint4*>(tmp) = vreg[i];
#pragma unroll
      for (int e = 0; e < 8; ++e) Vt[buf][dg * 8 + e][lane] = tmp[e];
    }
  };

  f32x4 acc[4];
#pragma unroll
  for (int d = 0; d < 4; ++d) acc[d] = {0.f, 0.f, 0.f, 0.f};
  float mrun[4] = {-1e30f, -1e30f, -1e30f, -1e30f};
  float lrun[4] = {0.f, 0.f, 0.f, 0.f};

  issueK(0, t_lo);
  issueV(t_lo);
  asm volatile("s_waitcnt vmcnt(0)" ::: "memory");
  writeV(0);
  __syncthreads();

  for (int tt = 0; tt < ntiles; ++tt) {
    const int buf = tt & 1;
    const int j0 = t_lo + tt * 64;
    if (tt + 1 < ntiles) {
      issueK(buf ^ 1, j0 + 64);
      issueV(j0 + 64);
    }

    f32x4 s[4];
#pragma unroll
    for (int n = 0; n < 4; ++n) {
      f32x4 z = {0.f, 0.f, 0.f, 0.f};
#pragma unroll
      for (int kc = 0; kc < 2; ++kc) {
        int row = n * 16 + l15;
        int unit = row * 8 + ((kc * 4 + g) ^ (row & 7));
        short8 kb = *reinterpret_cast<const short8*>(&Ks[buf][unit * 8]);
        z = __builtin_amdgcn_mfma_f32_16x16x32_bf16(qf[kc], kb, z, 0, 0, 0);
      }
      s[n] = z;
    }
#pragma unroll
    for (int n = 0; n < 4; ++n)
#pragma unroll
      for (int j = 0; j < 4; ++j) {
        int col = j0 + n * 16 + l15;
        int qr = qrow0 + g * 4 + j;
        int dlt = col - qr;
        float v = s[n][j] * 0.125f;
        s[n][j] = (dlt > 256 || dlt < -256) ? -1e30f : v;
      }
    float pn[4][4];
    float sold[4];
#pragma unroll
    for (int j = 0; j < 4; ++j) {
      float mx = fmaxf(fmaxf(s[0][j], s[1][j]), fmaxf(s[2][j], s[3][j]));
      mx = fmaxf(mx, __shfl_xor(mx, 1));
      mx = fmaxf(mx, __shfl_xor(mx, 2));
      mx = fmaxf(mx, __shfl_xor(mx, 4));
      mx = fmaxf(mx, __shfl_xor(mx, 8));
      float mnew = fmaxf(mrun[j], mx);
      float sc = __expf(mrun[j] - mnew);
      mrun[j] = mnew;
      sold[j] = sc;
      float rs = 0.f;
#pragma unroll
      for (int n = 0; n < 4; ++n) {
        float p = __expf(s[n][j] - mnew);
        pn[n][j] = p;
        rs += p;
      }
      rs += __shfl_xor(rs, 1);
      rs += __shfl_xor(rs, 2);
      rs += __shfl_xor(rs, 4);
      rs += __shfl_xor(rs, 8);
      lrun[j] = lrun[j] * sc + rs;
    }
#pragma unroll
    for (int d = 0; d < 4; ++d)
#pragma unroll
      for (int j = 0; j < 4; ++j) acc[d][j] *= sold[j];
#pragma unroll
    for (int n = 0; n < 4; ++n)
#pragma unroll
      for (int j = 0; j < 4; ++j)
        Pl[w][g * 4 + j][n * 16 + l15] = f2bf(pn[n][j]);
    asm volatile("s_waitcnt lgkmcnt(0)" ::: "memory");
    __builtin_amdgcn_sched_barrier(0);

    short8 pa[2];
    pa[0] = *reinterpret_cast<const short8*>(&Pl[w][l15][g * 8]);
    pa[1] = *reinterpret_cast<const short8*>(&Pl[w][l15][32 + g * 8]);
#pragma unroll
    for (int d = 0; d < 4; ++d) {
#pragma unroll
      for (int kc = 0; kc < 2; ++kc) {
        short8 vb = *reinterpret_cast<const short8*>(
            &Vt[buf][d * 16 + l15][kc * 32 + g * 8]);
        acc[d] = __builtin_amdgcn_mfma_f32_16x16x32_bf16(pa[kc], vb, acc[d], 0, 0, 0);
      }
    }

    if (tt + 1 < ntiles) {
      asm volatile("s_waitcnt vmcnt(0)" ::: "memory");
      writeV(buf ^ 1);
    }
    __syncthreads();
  }

  float inv[4];
#pragma unroll
  for (int j = 0; j < 4; ++j) inv[j] = 1.f / lrun[j];
#pragma unroll
  for (int d = 0; d < 4; ++d)
#pragma unroll
    for (int j = 0; j < 4; ++j) {
      float v = acc[d][j] * inv[j];
      Ctx[(size_t)(rowbase + qrow0 + g * 4 + j) * 512 + h * 64 + d * 16 + l15] =
          f2bf(v);
    }
}

// ---------------------------------------------------------------- residual + LayerNorm
__global__ __launch_bounds__(256) void ln_kernel(
    const float* __restrict__ A, const float* __restrict__ Bq,
    const float* __restrict__ G, const float* __restrict__ Bt,
    float* __restrict__ Out, ushort* __restrict__ OutB)
{
  const int lane = threadIdx.x & 63;
  const int wv = threadIdx.x >> 6;
  const int row = blockIdx.x * 4 + wv;
  const size_t base = (size_t)row * kD + lane * 8;

  float4 a0 = *reinterpret_cast<const float4*>(&A[base]);
  float4 a1 = *reinterpret_cast<const float4*>(&A[base + 4]);
  float4 b0 = *reinterpret_cast<const float4*>(&Bq[base]);
  float4 b1 = *reinterpret_cast<const float4*>(&Bq[base + 4]);
  float x[8] = {a0.x + b0.x, a0.y + b0.y, a0.z + b0.z, a0.w + b0.w,
                a1.x + b1.x, a1.y + b1.y, a1.z + b1.z, a1.w + b1.w};
  float s = 0.f, ss = 0.f;
#pragma unroll
  for (int i = 0; i < 8; ++i) { s += x[i]; ss += x[i] * x[i]; }
#pragma unroll
  for (int o = 1; o < 64; o <<= 1) {
    s += __shfl_xor(s, o, 64);
    ss += __shfl_xor(ss, o, 64);
  }
  const float mean = s * (1.f / kD);
  const float var = ss * (1.f / kD) - mean * mean;
  const float rs = rsqrtf(var + 1e-5f);

  const int c = lane * 8;
  float4 g0 = *reinterpret_cast<const float4*>(&G[c]);
  float4 g1 = *reinterpret_cast<const float4*>(&G[c + 4]);
  float4 t0 = *reinterpret_cast<const float4*>(&Bt[c]);
  float4 t1 = *reinterpret_cast<const float4*>(&Bt[c + 4]);
  float y[8];
  y[0] = (x[0] - mean) * rs * g0.x + t0.x;
  y[1] = (x[1] - mean) * rs * g0.y + t0.y;
  y[2] = (x[2] - mean) * rs * g0.z + t0.z;
  y[3] = (x[3] - mean) * rs * g0.w + t0.w;
  y[4] = (x[4] - mean) * rs * g1.x + t1.x;
  y[5] = (x[5] - mean) * rs * g1.y + t1.y;
  y[6] = (x[6] - mean) * rs * g1.z + t1.z;
  y[7] = (x[7] - mean) * rs * g1.w + t1.w;
  *reinterpret_cast<float4*>(&Out[base]) = {y[0], y[1], y[2], y[3]};
  *reinterpret_cast<float4*>(&Out[base + 4]) = {y[4], y[5], y[6], y[7]};
  if (OutB) {
    ushort ob[8];
#pragma unroll
    for (int i = 0; i < 8; ++i) ob[i] = f2bf(y[i]);
    *reinterpret_cast<uint4*>(&OutB[base]) = *reinterpret_cast<uint4*>(ob);
  }
}

// ---------------------------------------------------------------- launch
extern "C" void kernel_launch(void* const* d_in, const int* in_sizes, int n_in,
                              void* d_out, int out_size, void* d_ws, size_t ws_size,
                              hipStream_t stream)
{
  const float* x   = (const float*)d_in[0];
  const float* cw  = (const float*)d_in[2];
  const float* cb  = (const float*)d_in[3];
  const float* ipw = (const float*)d_in[4];
  const float* ipb = (const float*)d_in[5];
  const float* opw = (const float*)d_in[6];
  const float* opb = (const float*)d_in[7];
  const float* g1  = (const float*)d_in[8];
  const float* b1n = (const float*)d_in[9];
  const float* w1  = (const float*)d_in[10];
  const float* bb1 = (const float*)d_in[11];
  const float* w2  = (const float*)d_in[12];
  const float* bb2 = (const float*)d_in[13];
  const float* g2  = (const float*)d_in[14];
  const float* b2n = (const float*)d_in[15];
  float* out = (float*)d_out;

  char* p = (char*)d_ws;
  auto take = [&](size_t bytes) {
    char* q = p; p += (bytes + 255) & ~size_t(255); return q;
  };
  ushort* xb    = (ushort*)take((size_t)kN * kD * 2);
  char*  acat_r =          take((size_t)kN * 3 * kD * 2);   // 12MB region
  ushort* acat  = (ushort*)acat_r;
  ushort* wct   = (ushort*)take((size_t)3 * kD * kD * 2);
  ushort* wveff = (ushort*)take((size_t)kD * 3 * kD * 2);
  ushort* ipwb  = (ushort*)take((size_t)3 * kD * kD * 2);
  ushort* opwb  = (ushort*)take((size_t)kD * kD * 2);
  ushort* w1b   = (ushort*)take((size_t)2 * kD * kD * 2);
  ushort* w2b   = (ushort*)take((size_t)2 * kD * kD * 2);
  float* bvpart = (float*)take(4096 * 4);
  float* bveff  = (float*)take(512 * 4);
  char*  qk_r   =          take((size_t)kN * 2 * kD * 2);   // 8MB bf16 q|k
  ushort* qkb   = (ushort*)qk_r;
  ushort* vbb   = (ushort*)take((size_t)kN * kD * 2);
  ushort* ctx   = (ushort*)take((size_t)kN * kD * 2);
  float* hbuf   = (float*)take((size_t)kN * kD * 4);
  ushort* hb    = (ushort*)take((size_t)kN * kD * 2);
  float* attno  = (float*)acat_r;    // acat dead after qkv
  ushort* f1    = (ushort*)qk_r;     // qkb dead after attention
  float* f2     = (float*)acat_r;    // attno dead after LN1

  dim3 blk(256);
  // P0: prep (casts + wct + im2col + bias partials)
  prep_kernel<<<dim3(2048), blk, 0, stream>>>(
      x, ipw, opw, w1, w2, cw, cb,
      xb, ipwb, opwb, w1b, w2b, wct, acat, bvpart);
  // P1: Wv_eff = Wv @ Wc  (+ bveff reduce)
  wprep_kernel<<<dim3(192), blk, 0, stream>>>(
      ipwb, wct, wveff, ipb, bvpart, bveff);
  // P2: q,k,v in one launch (v = fused conv+proj, K=1536)
  qkv_kernel<<<dim3(1536), blk, 0, stream>>>(
      xb, acat, ipwb, ipb, wveff, bveff, qkb, vbb);
  // P3: banded MFMA attention -> bf16 ctx
  attn_mfma<<<dim3(kT / 64, kB * 8), blk, 0, stream>>>(qkb, vbb, ctx);
  // P4: out projection -> fp32
  gemm_bf16<float, 0><<<dim3(kN / 64, kD / 64), blk, 0, stream>>>(
      ctx, opwb, opb, attno, kD, kD);
  // P5: h = LN(x + attn_out)
  ln_kernel<<<dim3(kN / 4), blk, 0, stream>>>(x, attno, g1, b1n, hbuf, hb);
  // P6: ffn1 = relu(h @ w1^T + b1) -> bf16
  gemm_bf16<ushort, 1><<<dim3(kN / 64, 1024 / 64), blk, 0, stream>>>(
      hb, w1b, bb1, f1, 1024, kD);
  // P7: ffn2 -> fp32
  gemm_bf16<float, 0><<<dim3(kN / 64, kD / 64), blk, 0, stream>>>(
      f1, w2b, bb2, f2, kD, 2 * kD);
  // P8: out = LN(h + ffn2)
  ln_kernel<<<dim3(kN / 4), blk, 0, stream>>>(hbuf, f2, g2, b2n, out, nullptr);
}